// Round 3
// baseline (968.176 us; speedup 1.0000x reference)
//
#include <hip/hip_runtime.h>
#include <hip/hip_bf16.h>

// GCN: N=50000 nodes, E=800000 edges, hidden 64, 5 convs (relu on first 4).
// Dtypes: all float tensors are f32, edge_index int32, d_out f32[N].
// ws_size is between ~20 and ~26 MB (round-1 fault at 26.0 MB, round-2 OK at 19.8 MB),
// so the post-matmul feature buffer h is stored bf16 to keep footprint at 19.6 MB.
// Workspace: dinv f32[N] | z f32[N] | bufY f32[N*64] | bufH bf16[N*64]  = 19.6 MB

#define TPB 256
typedef __hip_bfloat16 bf16;

__global__ void k_init_deg(float* __restrict__ deg, int n) {
    int i = blockIdx.x * blockDim.x + threadIdx.x;
    if (i < n) deg[i] = 1.0f;  // self-loop
}

__global__ void k_count_deg(const int* __restrict__ dst, float* __restrict__ deg, int E, int n) {
    int e = blockIdx.x * blockDim.x + threadIdx.x;
    if (e < E) {
        int d = dst[e];
        if ((unsigned)d < (unsigned)n) atomicAdd(&deg[d], 1.0f);
    }
}

__global__ void k_rsqrt(float* __restrict__ d, int n) {
    int i = blockIdx.x * blockDim.x + threadIdx.x;
    if (i < n) d[i] = rsqrtf(d[i]);
}

// h[i][j] = sum_{k<4} x[i][k] * W[k][j]   (input layer matmul, bias added after agg)
__global__ void k_mm_in(const float* __restrict__ x, const float* __restrict__ W,
                        bf16* __restrict__ h, int n) {
    int t = blockIdx.x * blockDim.x + threadIdx.x;
    if (t >= n * 64) return;
    int i = t >> 6, j = t & 63;
    float acc = 0.f;
#pragma unroll
    for (int k = 0; k < 4; ++k) acc = fmaf(x[i * 4 + k], W[k * 64 + j], acc);
    h[t] = __float2bfloat16(acc);
}

// h[i][j] = sum_k relu(y[i][k] + bias[k]) * W[k][j]; 4 rows/block, W staged in LDS
__global__ void k_mm_h(const float* __restrict__ y, const float* __restrict__ bias,
                       const float* __restrict__ W, bf16* __restrict__ h, int n) {
    __shared__ float sW[64 * 64];
    __shared__ float sIn[4][64];
    int tid = threadIdx.x;
    for (int k = tid; k < 64 * 64; k += TPB) sW[k] = W[k];
    int r = tid >> 6, j = tid & 63;
    int row = blockIdx.x * 4 + r;
    float v = 0.f;
    if (row < n) v = fmaxf(y[row * 64 + j] + bias[j], 0.f);
    sIn[r][j] = v;
    __syncthreads();
    if (row >= n) return;
    float acc = 0.f;
#pragma unroll
    for (int k = 0; k < 64; ++k) acc = fmaf(sIn[r][k], sW[k * 64 + j], acc);
    h[row * 64 + j] = __float2bfloat16(acc);
}

// self-loop term: y[i][j] = h[i][j] * dinv[i]^2   (fully initializes y)
__global__ void k_agg_init(const bf16* __restrict__ h, const float* __restrict__ dinv,
                           float* __restrict__ y, int n) {
    int t = blockIdx.x * blockDim.x + threadIdx.x;
    if (t >= n * 64) return;
    int i = t >> 6;
    float di = dinv[i];
    y[t] = __bfloat162float(h[t]) * di * di;
}

// one 64-lane group per edge, lane = feature
__global__ void k_agg_edge(const int* __restrict__ src, const int* __restrict__ dst,
                           const float* __restrict__ dinv, const bf16* __restrict__ h,
                           float* __restrict__ y, int E, int n) {
    int t = blockIdx.x * blockDim.x + threadIdx.x;
    int e = t >> 6;
    if (e >= E) return;
    int j = t & 63;
    int s = src[e], d = dst[e];
    if ((unsigned)s >= (unsigned)n || (unsigned)d >= (unsigned)n) return;
    float norm = dinv[s] * dinv[d];
    atomicAdd(&y[d * 64 + j], __bfloat162float(h[s * 64 + j]) * norm);
}

// z[i] = sum_k relu(y[i][k] + bias[k]) * Wout[k]   (one wave per node)
__global__ void k_z(const float* __restrict__ y, const float* __restrict__ bias,
                    const float* __restrict__ Wout, float* __restrict__ z, int n) {
    int t = blockIdx.x * blockDim.x + threadIdx.x;
    int i = t >> 6, k = t & 63;
    if (i >= n) return;
    float v = fmaxf(y[i * 64 + k] + bias[k], 0.f) * Wout[k];
#pragma unroll
    for (int off = 32; off > 0; off >>= 1) v += __shfl_down(v, off);
    if (k == 0) z[i] = v;
}

// out[i] = z[i]*dinv[i]^2 + b_out  (fully initializes poisoned d_out)
__global__ void k_out_init(const float* __restrict__ z, const float* __restrict__ dinv,
                           const float* __restrict__ b_out, float* __restrict__ out, int n) {
    int i = blockIdx.x * blockDim.x + threadIdx.x;
    if (i < n) {
        float di = dinv[i];
        out[i] = z[i] * di * di + b_out[0];
    }
}

__global__ void k_out_edge(const int* __restrict__ src, const int* __restrict__ dst,
                           const float* __restrict__ dinv, const float* __restrict__ z,
                           float* __restrict__ out, int E, int n) {
    int e = blockIdx.x * blockDim.x + threadIdx.x;
    if (e < E) {
        int s = src[e], d = dst[e];
        if ((unsigned)s >= (unsigned)n || (unsigned)d >= (unsigned)n) return;
        atomicAdd(&out[d], z[s] * dinv[s] * dinv[d]);
    }
}

extern "C" void kernel_launch(void* const* d_in, const int* in_sizes, int n_in,
                              void* d_out, int out_size, void* d_ws, size_t ws_size,
                              hipStream_t stream) {
    const float* x     = (const float*)d_in[0];
    const int*   ei    = (const int*)d_in[1];
    const float* W_in  = (const float*)d_in[2];
    const float* b_in  = (const float*)d_in[3];
    const float* W_h   = (const float*)d_in[4];
    const float* b_h   = (const float*)d_in[5];
    const float* W_out = (const float*)d_in[6];
    const float* b_out = (const float*)d_in[7];
    float* out = (float*)d_out;

    int N = in_sizes[0] / 4;
    int E = in_sizes[1] / 2;
    const int* src = ei;
    const int* dst = ei + E;

    char* ws = (char*)d_ws;
    float* dinv = (float*)ws;  ws += (size_t)N * 4;
    float* z    = (float*)ws;  ws += (size_t)N * 4;
    float* bufY = (float*)ws;  ws += (size_t)N * 64 * 4;
    bf16*  bufH = (bf16*)ws;   // N*64*2 bytes; total = 19.6 MB

    int gN  = (N + TPB - 1) / TPB;
    int gE  = (E + TPB - 1) / TPB;
    int gNF = (N * 64 + TPB - 1) / TPB;
    int gE4 = (E + 3) / 4;   // 4 edges/block (64 lanes per edge)
    int gN4 = (N + 3) / 4;   // 4 rows/block

    // norm precompute
    k_init_deg<<<gN, TPB, 0, stream>>>(dinv, N);
    k_count_deg<<<gE, TPB, 0, stream>>>(dst, dinv, E, N);
    k_rsqrt<<<gN, TPB, 0, stream>>>(dinv, N);

    // conv0: x @ W_in -> bufH; aggregate -> bufY
    k_mm_in<<<gNF, TPB, 0, stream>>>(x, W_in, bufH, N);
    k_agg_init<<<gNF, TPB, 0, stream>>>(bufH, dinv, bufY, N);
    k_agg_edge<<<gE4, TPB, 0, stream>>>(src, dst, dinv, bufH, bufY, E, N);

    // conv1..3: relu(bufY + bias_prev) @ W_h[l] -> bufH; aggregate -> bufY
    for (int l = 0; l < 3; ++l) {
        const float* bias = (l == 0) ? b_in : (b_h + (l - 1) * 64);
        k_mm_h<<<gN4, TPB, 0, stream>>>(bufY, bias, W_h + (size_t)l * 64 * 64, bufH, N);
        k_agg_init<<<gNF, TPB, 0, stream>>>(bufH, dinv, bufY, N);
        k_agg_edge<<<gE4, TPB, 0, stream>>>(src, dst, dinv, bufH, bufY, E, N);
    }

    // conv4 (64 -> 1): z = relu(bufY + b_h[2]) @ W_out; aggregate directly into d_out
    k_z<<<gN4, TPB, 0, stream>>>(bufY, b_h + 2 * 64, W_out, z, N);
    k_out_init<<<gN, TPB, 0, stream>>>(z, dinv, b_out, out, N);
    k_out_edge<<<gE, TPB, 0, stream>>>(src, dst, dinv, z, out, E, N);
}

// Round 4
// 538.844 us; speedup vs baseline: 1.7968x; 1.7968x over previous
//
#include <hip/hip_runtime.h>
#include <hip/hip_bf16.h>

// GCN: N=50000, E=800000, hidden 64, 5 convs (relu on first 4).
// Dtypes: f32 tensors, int32 edge_index, f32 d_out[N].  ws_size in [19.6, 26.0) MB.
// Round-3 evidence: scatter atomicAdd generated 200 MB HBM WRITE per layer (4x167us).
// This round: per-call CSR build + gather-side aggregation fused with bias/relu/next matmul.
// Workspace (~17.0 MB): hA bf16[N*64] | hB bf16[N*64] | bucket i32[E] | row_start i32[N+1]
//                       | cursor i32[N] | cnt i32[N] | dinv f32[N] | z f32[N] | bsum i32[257]

#define TPB 256
typedef __hip_bfloat16 bf16;

__global__ void k_zero_cnt(int* __restrict__ cnt, int n) {
    int i = blockIdx.x * blockDim.x + threadIdx.x;
    if (i < n) cnt[i] = 0;
}

__global__ void k_hist(const int* __restrict__ dst, int* __restrict__ cnt, int E, int n) {
    int e = blockIdx.x * blockDim.x + threadIdx.x;
    if (e < E) {
        int d = dst[e];
        if ((unsigned)d < (unsigned)n) atomicAdd(&cnt[d], 1);
    }
}

// per-256-chunk sums of cnt
__global__ void k_blocksum(const int* __restrict__ cnt, int* __restrict__ bsum, int n) {
    __shared__ int s[TPB];
    int i = blockIdx.x * TPB + threadIdx.x;
    s[threadIdx.x] = (i < n) ? cnt[i] : 0;
    __syncthreads();
    for (int off = TPB / 2; off > 0; off >>= 1) {
        if (threadIdx.x < off) s[threadIdx.x] += s[threadIdx.x + off];
        __syncthreads();
    }
    if (threadIdx.x == 0) bsum[blockIdx.x] = s[0];
}

// exclusive scan of up to 256 block sums (single block)
__global__ void k_scan_bsum(int* __restrict__ bsum, int nb) {
    __shared__ int s[TPB];
    int t = threadIdx.x;
    int v = (t < nb) ? bsum[t] : 0;
    s[t] = v;
    __syncthreads();
    for (int off = 1; off < TPB; off <<= 1) {
        int u = (t >= off) ? s[t - off] : 0;
        __syncthreads();
        s[t] += u;
        __syncthreads();
    }
    if (t < nb) bsum[t] = s[t] - v;  // exclusive
}

// per-chunk exclusive scan + offset -> row_start; also cursor copy and dinv
__global__ void k_scan_final(const int* __restrict__ cnt, const int* __restrict__ bsum,
                             int* __restrict__ row_start, int* __restrict__ cursor,
                             float* __restrict__ dinv, int n) {
    __shared__ int s[TPB];
    int t = threadIdx.x;
    int i = blockIdx.x * TPB + t;
    int v = (i < n) ? cnt[i] : 0;
    s[t] = v;
    __syncthreads();
    for (int off = 1; off < TPB; off <<= 1) {
        int u = (t >= off) ? s[t - off] : 0;
        __syncthreads();
        s[t] += u;
        __syncthreads();
    }
    if (i < n) {
        int excl = bsum[blockIdx.x] + s[t] - v;
        row_start[i] = excl;
        cursor[i] = excl;
        dinv[i] = rsqrtf((float)v + 1.0f);   // +1 self-loop
        if (i == n - 1) row_start[n] = excl + v;
    }
}

__global__ void k_scatter(const int* __restrict__ src, const int* __restrict__ dst,
                          int* __restrict__ cursor, int* __restrict__ bucket, int E, int n) {
    int e = blockIdx.x * blockDim.x + threadIdx.x;
    if (e < E) {
        int d = dst[e], s = src[e];
        if ((unsigned)d >= (unsigned)n || (unsigned)s >= (unsigned)n) return;
        int pos = atomicAdd(&cursor[d], 1);
        bucket[pos] = s;
    }
}

// h1[i][j] = sum_{k<4} x[i][k] * W_in[k][j]  (one wave per node, lane=feature)
__global__ void k_mm_in(const float* __restrict__ x, const float* __restrict__ W,
                        bf16* __restrict__ h, int n) {
    int t = blockIdx.x * blockDim.x + threadIdx.x;
    if (t >= n * 64) return;
    int i = t >> 6, j = t & 63;
    float acc = 0.f;
#pragma unroll
    for (int k = 0; k < 4; ++k) acc = fmaf(x[i * 4 + k], W[k * 64 + j], acc);
    h[t] = __float2bfloat16(acc);
}

// Fused: y[d] = agg(hIn)[d] + bias; a = relu(y); hOut[d] = a @ W.
// One wave per node (4 nodes/block), lane = feature. W staged in LDS.
__global__ __launch_bounds__(TPB) void k_gconv(
    const bf16* __restrict__ hIn, const float* __restrict__ dinv,
    const int* __restrict__ row_start, const int* __restrict__ bucket,
    const float* __restrict__ bias, const float* __restrict__ W,
    bf16* __restrict__ hOut, int n) {
    __shared__ float sW[64 * 64];
    __shared__ float sV[4][64];
    int tid = threadIdx.x;
    for (int k = tid; k < 64 * 64; k += TPB) sW[k] = W[k];
    int r = tid >> 6, j = tid & 63;
    int d = blockIdx.x * 4 + r;
    float v = 0.f;
    if (d < n) {
        float dd = dinv[d];
        float acc = __bfloat162float(hIn[d * 64 + j]) * dd * dd;  // self-loop
        int k0 = row_start[d], k1 = row_start[d + 1];
        for (int k = k0; k < k1; ++k) {
            int s = bucket[k];                                    // wave-uniform broadcast
            acc = fmaf(__bfloat162float(hIn[s * 64 + j]), dinv[s] * dd, acc);
        }
        v = fmaxf(acc + bias[j], 0.f);
    }
    sV[r][j] = v;
    __syncthreads();
    if (d >= n) return;
    float acc2 = 0.f;
#pragma unroll
    for (int k = 0; k < 64; ++k) acc2 = fmaf(sV[r][k], sW[k * 64 + j], acc2);
    hOut[d * 64 + j] = __float2bfloat16(acc2);
}

// Last hidden conv fused with the 64->1 output matmul: z[d] = relu(agg(hIn)[d]+bias) . Wout
__global__ __launch_bounds__(TPB) void k_gconv_z(
    const bf16* __restrict__ hIn, const float* __restrict__ dinv,
    const int* __restrict__ row_start, const int* __restrict__ bucket,
    const float* __restrict__ bias, const float* __restrict__ Wout,
    float* __restrict__ z, int n) {
    int t = blockIdx.x * blockDim.x + threadIdx.x;
    int d = t >> 6, j = t & 63;
    if (d >= n) return;
    float dd = dinv[d];
    float acc = __bfloat162float(hIn[d * 64 + j]) * dd * dd;
    int k0 = row_start[d], k1 = row_start[d + 1];
    for (int k = k0; k < k1; ++k) {
        int s = bucket[k];
        acc = fmaf(__bfloat162float(hIn[s * 64 + j]), dinv[s] * dd, acc);
    }
    float v = fmaxf(acc + bias[j], 0.f) * Wout[j];
#pragma unroll
    for (int off = 32; off > 0; off >>= 1) v += __shfl_down(v, off);
    if (j == 0) z[d] = v;
}

// out[d] = z[d]*dinv[d]^2 + sum_in z[s]*dinv[s]*dinv[d] + b_out  (one thread per node)
__global__ void k_out(const float* __restrict__ z, const float* __restrict__ dinv,
                      const int* __restrict__ row_start, const int* __restrict__ bucket,
                      const float* __restrict__ b_out, float* __restrict__ out, int n) {
    int d = blockIdx.x * blockDim.x + threadIdx.x;
    if (d >= n) return;
    float dd = dinv[d];
    float acc = z[d] * dd * dd;
    int k0 = row_start[d], k1 = row_start[d + 1];
    for (int k = k0; k < k1; ++k) {
        int s = bucket[k];
        acc = fmaf(z[s], dinv[s] * dd, acc);
    }
    out[d] = acc + b_out[0];
}

extern "C" void kernel_launch(void* const* d_in, const int* in_sizes, int n_in,
                              void* d_out, int out_size, void* d_ws, size_t ws_size,
                              hipStream_t stream) {
    const float* x     = (const float*)d_in[0];
    const int*   ei    = (const int*)d_in[1];
    const float* W_in  = (const float*)d_in[2];
    const float* b_in  = (const float*)d_in[3];
    const float* W_h   = (const float*)d_in[4];
    const float* b_h   = (const float*)d_in[5];
    const float* W_out = (const float*)d_in[6];
    const float* b_out = (const float*)d_in[7];
    float* out = (float*)d_out;

    int N = in_sizes[0] / 4;
    int E = in_sizes[1] / 2;
    const int* src = ei;
    const int* dst = ei + E;

    char* ws = (char*)d_ws;
    bf16* hA        = (bf16*)ws;   ws += (size_t)N * 64 * 2;
    bf16* hB        = (bf16*)ws;   ws += (size_t)N * 64 * 2;
    int*  bucket    = (int*)ws;    ws += (size_t)E * 4;
    int*  row_start = (int*)ws;    ws += (size_t)(N + 1) * 4;
    int*  cursor    = (int*)ws;    ws += (size_t)N * 4;
    int*  cnt       = (int*)ws;    ws += (size_t)N * 4;
    float* dinv     = (float*)ws;  ws += (size_t)N * 4;
    float* z        = (float*)ws;  ws += (size_t)N * 4;
    int*  bsum      = (int*)ws;    // 257 ints

    int gN  = (N + TPB - 1) / TPB;       // also the scan chunk count (<=256 for N<=65536)
    int gE  = (E + TPB - 1) / TPB;
    int gNF = (N * 64 + TPB - 1) / TPB;
    int gN4 = (N + 3) / 4;               // 4 nodes/block (1 wave per node)

    // ---- CSR build + norms ----
    k_zero_cnt<<<gN, TPB, 0, stream>>>(cnt, N);
    k_hist<<<gE, TPB, 0, stream>>>(dst, cnt, E, N);
    k_blocksum<<<gN, TPB, 0, stream>>>(cnt, bsum, N);
    k_scan_bsum<<<1, TPB, 0, stream>>>(bsum, gN);
    k_scan_final<<<gN, TPB, 0, stream>>>(cnt, bsum, row_start, cursor, dinv, N);
    k_scatter<<<gE, TPB, 0, stream>>>(src, dst, cursor, bucket, E, N);

    // ---- layers ----
    k_mm_in<<<gNF, TPB, 0, stream>>>(x, W_in, hA, N);                                  // h1
    k_gconv<<<gN4, TPB, 0, stream>>>(hA, dinv, row_start, bucket, b_in, W_h, hB, N);   // y1,h2
    k_gconv<<<gN4, TPB, 0, stream>>>(hB, dinv, row_start, bucket, b_h, W_h + 4096, hA, N);       // y2,h3
    k_gconv<<<gN4, TPB, 0, stream>>>(hA, dinv, row_start, bucket, b_h + 64, W_h + 8192, hB, N);  // y3,h4
    k_gconv_z<<<gN4, TPB, 0, stream>>>(hB, dinv, row_start, bucket, b_h + 128, W_out, z, N);     // y4,z
    k_out<<<gN, TPB, 0, stream>>>(z, dinv, row_start, bucket, b_out, out, N);          // conv4
}

// Round 6
// 375.914 us; speedup vs baseline: 2.5755x; 1.4334x over previous
//
#include <hip/hip_runtime.h>
#include <hip/hip_bf16.h>

// GCN: N=50000, E=800000, hidden 64, 5 convs (relu on first 4).
// f32 tensors, int32 edge_index, f32 d_out[N].  ws_size in [19.8, 26.0) MB.
// Round-5 core-dumped with no identifiable OOB in the diff vs passing round-4;
// suspects: rocprof per-group replay re-running k_scatter without re-running the
// cursor init (cursor grows past E -> bucket OOB writes), or infra flake.
// This round: every CSR producer/consumer is clamped (pos<E, k-range<=E, s<=N-1,
// ~1 v_min_u32 per edge = noise), k_out grid fixed, and round-5's perf ideas kept:
// premultiplied features (g = h*dinv, no per-edge dinv gather) + x4-unrolled gather.
// Workspace (~17.0 MB): gA bf16[N*64] | gB bf16[N*64] | bucket i32[E] | row_start i32[N+1]
//                       | cursor i32[N] | cnt i32[N] | dinv f32[N] | zg f32[N] | bsum i32[257]

#define TPB 256
typedef __hip_bfloat16 bf16;
#define B2F __bfloat162float

__global__ void k_zero_cnt(int* __restrict__ cnt, int n) {
    int i = blockIdx.x * blockDim.x + threadIdx.x;
    if (i < n) cnt[i] = 0;
}

__global__ void k_hist(const int* __restrict__ dst, int* __restrict__ cnt, int E, int n) {
    int e = blockIdx.x * blockDim.x + threadIdx.x;
    if (e < E) {
        int d = dst[e];
        if ((unsigned)d < (unsigned)n) atomicAdd(&cnt[d], 1);
    }
}

__global__ void k_blocksum(const int* __restrict__ cnt, int* __restrict__ bsum, int n) {
    __shared__ int s[TPB];
    int i = blockIdx.x * TPB + threadIdx.x;
    s[threadIdx.x] = (i < n) ? cnt[i] : 0;
    __syncthreads();
    for (int off = TPB / 2; off > 0; off >>= 1) {
        if (threadIdx.x < off) s[threadIdx.x] += s[threadIdx.x + off];
        __syncthreads();
    }
    if (threadIdx.x == 0) bsum[blockIdx.x] = s[0];
}

__global__ void k_scan_bsum(int* __restrict__ bsum, int nb) {
    __shared__ int s[TPB];
    int t = threadIdx.x;
    int v = (t < nb) ? bsum[t] : 0;
    s[t] = v;
    __syncthreads();
    for (int off = 1; off < TPB; off <<= 1) {
        int u = (t >= off) ? s[t - off] : 0;
        __syncthreads();
        s[t] += u;
        __syncthreads();
    }
    if (t < nb) bsum[t] = s[t] - v;  // exclusive
}

__global__ void k_scan_final(const int* __restrict__ cnt, const int* __restrict__ bsum,
                             int* __restrict__ row_start, int* __restrict__ cursor,
                             float* __restrict__ dinv, int n) {
    __shared__ int s[TPB];
    int t = threadIdx.x;
    int i = blockIdx.x * TPB + t;
    int v = (i < n) ? cnt[i] : 0;
    s[t] = v;
    __syncthreads();
    for (int off = 1; off < TPB; off <<= 1) {
        int u = (t >= off) ? s[t - off] : 0;
        __syncthreads();
        s[t] += u;
        __syncthreads();
    }
    if (i < n) {
        int excl = bsum[blockIdx.x] + s[t] - v;
        row_start[i] = excl;
        cursor[i] = excl;
        dinv[i] = rsqrtf((float)v + 1.0f);   // +1 self-loop
        if (i == n - 1) row_start[n] = excl + v;
    }
}

__global__ void k_scatter(const int* __restrict__ src, const int* __restrict__ dst,
                          int* __restrict__ cursor, int* __restrict__ bucket, int E, int n) {
    int e = blockIdx.x * blockDim.x + threadIdx.x;
    if (e < E) {
        int d = dst[e], s = src[e];
        if ((unsigned)d >= (unsigned)n || (unsigned)s >= (unsigned)n) return;
        int pos = atomicAdd(&cursor[d], 1);
        if ((unsigned)pos < (unsigned)E) bucket[pos] = s;  // replay-safe clamp
    }
}

// g1[i][j] = (sum_{k<4} x[i][k] * W_in[k][j]) * dinv[i]   (premultiplied)
__global__ void k_mm_in(const float* __restrict__ x, const float* __restrict__ W,
                        const float* __restrict__ dinv, bf16* __restrict__ g, int n) {
    int t = blockIdx.x * blockDim.x + threadIdx.x;
    if (t >= n * 64) return;
    int i = t >> 6, j = t & 63;
    float acc = 0.f;
#pragma unroll
    for (int k = 0; k < 4; ++k) acc = fmaf(x[i * 4 + k], W[k * 64 + j], acc);
    g[t] = __float2bfloat16(acc * dinv[i]);
}

// neighbor-sum of premultiplied rows, x4 unroll (independent gather chains), clamped
__device__ __forceinline__ float agg_row(const bf16* __restrict__ g,
                                         const int* __restrict__ bucket,
                                         int k0, int k1, int j, float self, unsigned nm1) {
    float a0 = self, a1 = 0.f, a2 = 0.f, a3 = 0.f;
    int k = k0;
    int kend4 = k0 + ((k1 - k0) & ~3);
    for (; k < kend4; k += 4) {
        unsigned s0 = min((unsigned)bucket[k + 0], nm1);
        unsigned s1 = min((unsigned)bucket[k + 1], nm1);
        unsigned s2 = min((unsigned)bucket[k + 2], nm1);
        unsigned s3 = min((unsigned)bucket[k + 3], nm1);
        a0 += B2F(g[s0 * 64 + j]);
        a1 += B2F(g[s1 * 64 + j]);
        a2 += B2F(g[s2 * 64 + j]);
        a3 += B2F(g[s3 * 64 + j]);
    }
    for (; k < k1; ++k) {
        unsigned s = min((unsigned)bucket[k], nm1);
        a0 += B2F(g[s * 64 + j]);
    }
    return (a0 + a1) + (a2 + a3);
}

// Fused: y[d] = dd*(g[d] + sum g[s]) + bias; a = relu(y); gOut[d] = (a @ W) * dd.
// One wave per node (4 nodes/block), lane = feature. W staged in LDS.
__global__ __launch_bounds__(TPB) void k_gconv(
    const bf16* __restrict__ gIn, const float* __restrict__ dinv,
    const int* __restrict__ row_start, const int* __restrict__ bucket,
    const float* __restrict__ bias, const float* __restrict__ W,
    bf16* __restrict__ gOut, int n, int E) {
    __shared__ float sW[64 * 64];
    __shared__ float sV[4][64];
    int tid = threadIdx.x;
    for (int k = tid; k < 64 * 64; k += TPB) sW[k] = W[k];
    int r = tid >> 6, j = tid & 63;
    int d = blockIdx.x * 4 + r;
    float v = 0.f, dd = 0.f;
    if (d < n) {
        dd = dinv[d];
        int k0 = row_start[d], k1 = row_start[d + 1];
        k1 = min(k1, E); k0 = max(min(k0, k1), 0);       // clamp range
        float sum = agg_row(gIn, bucket, k0, k1, j, B2F(gIn[d * 64 + j]), (unsigned)(n - 1));
        v = fmaxf(fmaf(sum, dd, bias[j]), 0.f);
    }
    sV[r][j] = v;
    __syncthreads();
    if (d >= n) return;
    float acc2 = 0.f;
#pragma unroll
    for (int k = 0; k < 64; ++k) acc2 = fmaf(sV[r][k], sW[k * 64 + j], acc2);
    gOut[d * 64 + j] = __float2bfloat16(acc2 * dd);
}

// Last hidden conv fused with 64->1 matmul: zg[d] = (relu(y4[d]) . Wout) * dd
__global__ __launch_bounds__(TPB) void k_gconv_z(
    const bf16* __restrict__ gIn, const float* __restrict__ dinv,
    const int* __restrict__ row_start, const int* __restrict__ bucket,
    const float* __restrict__ bias, const float* __restrict__ Wout,
    float* __restrict__ zg, int n, int E) {
    int t = blockIdx.x * blockDim.x + threadIdx.x;
    int d = t >> 6, j = t & 63;
    if (d >= n) return;
    float dd = dinv[d];
    int k0 = row_start[d], k1 = row_start[d + 1];
    k1 = min(k1, E); k0 = max(min(k0, k1), 0);
    float sum = agg_row(gIn, bucket, k0, k1, j, B2F(gIn[d * 64 + j]), (unsigned)(n - 1));
    float v = fmaxf(fmaf(sum, dd, bias[j]), 0.f) * Wout[j];
#pragma unroll
    for (int off = 32; off > 0; off >>= 1) v += __shfl_down(v, off);
    if (j == 0) zg[d] = v * dd;
}

// out[d] = dd*(zg[d] + sum zg[s]) + b_out.  One wave per node, lane = neighbor.
__global__ __launch_bounds__(TPB) void k_out(
    const float* __restrict__ zg, const float* __restrict__ dinv,
    const int* __restrict__ row_start, const int* __restrict__ bucket,
    const float* __restrict__ b_out, float* __restrict__ out, int n, int E) {
    int t = blockIdx.x * blockDim.x + threadIdx.x;
    int d = t >> 6, lane = t & 63;
    if (d >= n) return;
    int k0 = row_start[d], k1 = row_start[d + 1];
    k1 = min(k1, E); k0 = max(min(k0, k1), 0);
    unsigned nm1 = (unsigned)(n - 1);
    float v = 0.f;
    for (int k = k0 + lane; k < k1; k += 64) {
        unsigned s = min((unsigned)bucket[k], nm1);
        v += zg[s];
    }
#pragma unroll
    for (int off = 32; off > 0; off >>= 1) v += __shfl_down(v, off);
    if (lane == 0) out[d] = fmaf(zg[d] + v, dinv[d], b_out[0]);
}

extern "C" void kernel_launch(void* const* d_in, const int* in_sizes, int n_in,
                              void* d_out, int out_size, void* d_ws, size_t ws_size,
                              hipStream_t stream) {
    const float* x     = (const float*)d_in[0];
    const int*   ei    = (const int*)d_in[1];
    const float* W_in  = (const float*)d_in[2];
    const float* b_in  = (const float*)d_in[3];
    const float* W_h   = (const float*)d_in[4];
    const float* b_h   = (const float*)d_in[5];
    const float* W_out = (const float*)d_in[6];
    const float* b_out = (const float*)d_in[7];
    float* out = (float*)d_out;

    int N = in_sizes[0] / 4;
    int E = in_sizes[1] / 2;
    const int* src = ei;
    const int* dst = ei + E;

    char* ws = (char*)d_ws;
    bf16* gA        = (bf16*)ws;   ws += (size_t)N * 64 * 2;
    bf16* gB        = (bf16*)ws;   ws += (size_t)N * 64 * 2;
    int*  bucket    = (int*)ws;    ws += (size_t)E * 4;
    int*  row_start = (int*)ws;    ws += (size_t)(N + 1) * 4;
    int*  cursor    = (int*)ws;    ws += (size_t)N * 4;
    int*  cnt       = (int*)ws;    ws += (size_t)N * 4;
    float* dinv     = (float*)ws;  ws += (size_t)N * 4;
    float* zg       = (float*)ws;  ws += (size_t)N * 4;
    int*  bsum      = (int*)ws;    // 257 ints

    int gN  = (N + TPB - 1) / TPB;       // scan chunk count (<=256 for N<=65536)
    int gE  = (E + TPB - 1) / TPB;
    int gNF = (N * 64 + TPB - 1) / TPB;
    int gN4 = (N + 3) / 4;               // 4 nodes/block (1 wave per node)

    // ---- CSR build + norms ----
    k_zero_cnt<<<gN, TPB, 0, stream>>>(cnt, N);
    k_hist<<<gE, TPB, 0, stream>>>(dst, cnt, E, N);
    k_blocksum<<<gN, TPB, 0, stream>>>(cnt, bsum, N);
    k_scan_bsum<<<1, TPB, 0, stream>>>(bsum, gN);
    k_scan_final<<<gN, TPB, 0, stream>>>(cnt, bsum, row_start, cursor, dinv, N);
    k_scatter<<<gE, TPB, 0, stream>>>(src, dst, cursor, bucket, E, N);

    // ---- layers (all feature buffers premultiplied by dinv) ----
    k_mm_in<<<gNF, TPB, 0, stream>>>(x, W_in, dinv, gA, N);
    k_gconv<<<gN4, TPB, 0, stream>>>(gA, dinv, row_start, bucket, b_in, W_h, gB, N, E);
    k_gconv<<<gN4, TPB, 0, stream>>>(gB, dinv, row_start, bucket, b_h, W_h + 4096, gA, N, E);
    k_gconv<<<gN4, TPB, 0, stream>>>(gA, dinv, row_start, bucket, b_h + 64, W_h + 8192, gB, N, E);
    k_gconv_z<<<gN4, TPB, 0, stream>>>(gB, dinv, row_start, bucket, b_h + 128, W_out, zg, N, E);
    k_out<<<gN4, TPB, 0, stream>>>(zg, dinv, row_start, bucket, b_out, out, N, E);
}

// Round 7
// 351.294 us; speedup vs baseline: 2.7560x; 1.0701x over previous
//
#include <hip/hip_runtime.h>
#include <hip/hip_bf16.h>

// GCN: N=50000, E=800000, hidden 64, 5 convs (relu on first 4).
// f32 tensors, int32 edge_index, f32 d_out[N].  ws_size in [19.8, 26.0) MB.
// Round-6: 376 us, k_gconv 57 us, VALUBusy 33% / HBM 9% => still gather-latency-bound;
// each edge paid a full-wave bucket load + dependent feature load (2 serialized waits).
// This round: neighbor indices register-staged (1 coalesced load / 64 edges) and
// extracted via readlane => SGPR index, scalar address math, only the feature load on
// the critical path; x8 unroll = 8 outstanding loads/wave. Clamps kept (scalar, free).
// Workspace (~17.0 MB): gA bf16[N*64] | gB bf16[N*64] | bucket i32[E] | row_start i32[N+1]
//                       | cursor i32[N] | cnt i32[N] | dinv f32[N] | zg f32[N] | bsum i32[257]

#define TPB 256
typedef __hip_bfloat16 bf16;
#define B2F __bfloat162float

__global__ void k_zero_cnt(int* __restrict__ cnt, int n) {
    int i = blockIdx.x * blockDim.x + threadIdx.x;
    if (i < n) cnt[i] = 0;
}

__global__ void k_hist(const int* __restrict__ dst, int* __restrict__ cnt, int E, int n) {
    int e = blockIdx.x * blockDim.x + threadIdx.x;
    if (e < E) {
        int d = dst[e];
        if ((unsigned)d < (unsigned)n) atomicAdd(&cnt[d], 1);
    }
}

__global__ void k_blocksum(const int* __restrict__ cnt, int* __restrict__ bsum, int n) {
    __shared__ int s[TPB];
    int i = blockIdx.x * TPB + threadIdx.x;
    s[threadIdx.x] = (i < n) ? cnt[i] : 0;
    __syncthreads();
    for (int off = TPB / 2; off > 0; off >>= 1) {
        if (threadIdx.x < off) s[threadIdx.x] += s[threadIdx.x + off];
        __syncthreads();
    }
    if (threadIdx.x == 0) bsum[blockIdx.x] = s[0];
}

__global__ void k_scan_bsum(int* __restrict__ bsum, int nb) {
    __shared__ int s[TPB];
    int t = threadIdx.x;
    int v = (t < nb) ? bsum[t] : 0;
    s[t] = v;
    __syncthreads();
    for (int off = 1; off < TPB; off <<= 1) {
        int u = (t >= off) ? s[t - off] : 0;
        __syncthreads();
        s[t] += u;
        __syncthreads();
    }
    if (t < nb) bsum[t] = s[t] - v;  // exclusive
}

__global__ void k_scan_final(const int* __restrict__ cnt, const int* __restrict__ bsum,
                             int* __restrict__ row_start, int* __restrict__ cursor,
                             float* __restrict__ dinv, int n) {
    __shared__ int s[TPB];
    int t = threadIdx.x;
    int i = blockIdx.x * TPB + t;
    int v = (i < n) ? cnt[i] : 0;
    s[t] = v;
    __syncthreads();
    for (int off = 1; off < TPB; off <<= 1) {
        int u = (t >= off) ? s[t - off] : 0;
        __syncthreads();
        s[t] += u;
        __syncthreads();
    }
    if (i < n) {
        int excl = bsum[blockIdx.x] + s[t] - v;
        row_start[i] = excl;
        cursor[i] = excl;
        dinv[i] = rsqrtf((float)v + 1.0f);   // +1 self-loop
        if (i == n - 1) row_start[n] = excl + v;
    }
}

__global__ void k_scatter(const int* __restrict__ src, const int* __restrict__ dst,
                          int* __restrict__ cursor, int* __restrict__ bucket, int E, int n) {
    int e = blockIdx.x * blockDim.x + threadIdx.x;
    if (e < E) {
        int d = dst[e], s = src[e];
        if ((unsigned)d >= (unsigned)n || (unsigned)s >= (unsigned)n) return;
        int pos = atomicAdd(&cursor[d], 1);
        if ((unsigned)pos < (unsigned)E) bucket[pos] = s;  // replay-safe clamp
    }
}

// g1[i][j] = (sum_{k<4} x[i][k] * W_in[k][j]) * dinv[i]   (premultiplied)
__global__ void k_mm_in(const float* __restrict__ x, const float* __restrict__ W,
                        const float* __restrict__ dinv, bf16* __restrict__ g, int n) {
    int t = blockIdx.x * blockDim.x + threadIdx.x;
    if (t >= n * 64) return;
    int i = t >> 6, j = t & 63;
    float acc = 0.f;
#pragma unroll
    for (int k = 0; k < 4; ++k) acc = fmaf(x[i * 4 + k], W[k * 64 + j], acc);
    g[t] = __float2bfloat16(acc * dinv[i]);
}

// neighbor-sum of premultiplied rows.  Indices register-staged (1 coalesced load per
// 64 edges) and extracted with readlane (k is wave-uniform) -> SGPR index, scalar
// address math, only the feature load on the critical path.  x8 independent chains.
__device__ __forceinline__ float agg_row(const bf16* __restrict__ g,
                                         const int* __restrict__ bucket,
                                         int k0, int k1, int j, float self,
                                         unsigned nm1, unsigned Em1) {
    float a0 = self, a1 = 0.f, a2 = 0.f, a3 = 0.f;
    float a4 = 0.f, a5 = 0.f, a6 = 0.f, a7 = 0.f;
    int lane = threadIdx.x & 63;
    for (int base = k0; base < k1; base += 64) {
        int cnt = min(64, k1 - base);
        unsigned addr = min((unsigned)(base + lane), Em1);
        int vb = bucket[addr];                    // coalesced; lane l holds edge base+l
        int k = 0;
        for (; k + 8 <= cnt; k += 8) {
            unsigned s0 = min((unsigned)__builtin_amdgcn_readlane(vb, k + 0), nm1);
            unsigned s1 = min((unsigned)__builtin_amdgcn_readlane(vb, k + 1), nm1);
            unsigned s2 = min((unsigned)__builtin_amdgcn_readlane(vb, k + 2), nm1);
            unsigned s3 = min((unsigned)__builtin_amdgcn_readlane(vb, k + 3), nm1);
            unsigned s4 = min((unsigned)__builtin_amdgcn_readlane(vb, k + 4), nm1);
            unsigned s5 = min((unsigned)__builtin_amdgcn_readlane(vb, k + 5), nm1);
            unsigned s6 = min((unsigned)__builtin_amdgcn_readlane(vb, k + 6), nm1);
            unsigned s7 = min((unsigned)__builtin_amdgcn_readlane(vb, k + 7), nm1);
            a0 += B2F(g[(size_t)s0 * 64 + j]);
            a1 += B2F(g[(size_t)s1 * 64 + j]);
            a2 += B2F(g[(size_t)s2 * 64 + j]);
            a3 += B2F(g[(size_t)s3 * 64 + j]);
            a4 += B2F(g[(size_t)s4 * 64 + j]);
            a5 += B2F(g[(size_t)s5 * 64 + j]);
            a6 += B2F(g[(size_t)s6 * 64 + j]);
            a7 += B2F(g[(size_t)s7 * 64 + j]);
        }
        for (; k < cnt; ++k) {
            unsigned s = min((unsigned)__builtin_amdgcn_readlane(vb, k), nm1);
            a0 += B2F(g[(size_t)s * 64 + j]);
        }
    }
    return ((a0 + a1) + (a2 + a3)) + ((a4 + a5) + (a6 + a7));
}

// Fused: y[d] = dd*(g[d] + sum g[s]) + bias; a = relu(y); gOut[d] = (a @ W) * dd.
// One wave per node (4 nodes/block), lane = feature. W staged in LDS.
__global__ __launch_bounds__(TPB) void k_gconv(
    const bf16* __restrict__ gIn, const float* __restrict__ dinv,
    const int* __restrict__ row_start, const int* __restrict__ bucket,
    const float* __restrict__ bias, const float* __restrict__ W,
    bf16* __restrict__ gOut, int n, int E) {
    __shared__ float sW[64 * 64];
    __shared__ float sV[4][64];
    int tid = threadIdx.x;
    for (int k = tid; k < 64 * 64; k += TPB) sW[k] = W[k];
    int r = tid >> 6, j = tid & 63;
    int d = blockIdx.x * 4 + r;
    float v = 0.f, dd = 0.f;
    if (d < n) {                                   // wave-uniform branch (d uniform)
        dd = dinv[d];
        int k0 = row_start[d], k1 = row_start[d + 1];
        k1 = min(k1, E); k0 = max(min(k0, k1), 0); // clamp range
        float sum = agg_row(gIn, bucket, k0, k1, j, B2F(gIn[d * 64 + j]),
                            (unsigned)(n - 1), (unsigned)(E - 1));
        v = fmaxf(fmaf(sum, dd, bias[j]), 0.f);
    }
    sV[r][j] = v;
    __syncthreads();
    if (d >= n) return;
    float acc2 = 0.f;
#pragma unroll
    for (int k = 0; k < 64; ++k) acc2 = fmaf(sV[r][k], sW[k * 64 + j], acc2);
    gOut[d * 64 + j] = __float2bfloat16(acc2 * dd);
}

// Last hidden conv fused with 64->1 matmul: zg[d] = (relu(y4[d]) . Wout) * dd
__global__ __launch_bounds__(TPB) void k_gconv_z(
    const bf16* __restrict__ gIn, const float* __restrict__ dinv,
    const int* __restrict__ row_start, const int* __restrict__ bucket,
    const float* __restrict__ bias, const float* __restrict__ Wout,
    float* __restrict__ zg, int n, int E) {
    int t = blockIdx.x * blockDim.x + threadIdx.x;
    int d = t >> 6, j = t & 63;                    // d uniform per wave
    if (d >= n) return;
    float dd = dinv[d];
    int k0 = row_start[d], k1 = row_start[d + 1];
    k1 = min(k1, E); k0 = max(min(k0, k1), 0);
    float sum = agg_row(gIn, bucket, k0, k1, j, B2F(gIn[d * 64 + j]),
                        (unsigned)(n - 1), (unsigned)(E - 1));
    float v = fmaxf(fmaf(sum, dd, bias[j]), 0.f) * Wout[j];
#pragma unroll
    for (int off = 32; off > 0; off >>= 1) v += __shfl_down(v, off);
    if (j == 0) zg[d] = v * dd;
}

// out[d] = dd*(zg[d] + sum zg[s]) + b_out.  One wave per node, lane = neighbor.
__global__ __launch_bounds__(TPB) void k_out(
    const float* __restrict__ zg, const float* __restrict__ dinv,
    const int* __restrict__ row_start, const int* __restrict__ bucket,
    const float* __restrict__ b_out, float* __restrict__ out, int n, int E) {
    int t = blockIdx.x * blockDim.x + threadIdx.x;
    int d = t >> 6, lane = t & 63;
    if (d >= n) return;
    int k0 = row_start[d], k1 = row_start[d + 1];
    k1 = min(k1, E); k0 = max(min(k0, k1), 0);
    unsigned nm1 = (unsigned)(n - 1);
    float v = 0.f;
    for (int k = k0 + lane; k < k1; k += 64) {
        unsigned s = min((unsigned)bucket[k], nm1);
        v += zg[s];
    }
#pragma unroll
    for (int off = 32; off > 0; off >>= 1) v += __shfl_down(v, off);
    if (lane == 0) out[d] = fmaf(zg[d] + v, dinv[d], b_out[0]);
}

extern "C" void kernel_launch(void* const* d_in, const int* in_sizes, int n_in,
                              void* d_out, int out_size, void* d_ws, size_t ws_size,
                              hipStream_t stream) {
    const float* x     = (const float*)d_in[0];
    const int*   ei    = (const int*)d_in[1];
    const float* W_in  = (const float*)d_in[2];
    const float* b_in  = (const float*)d_in[3];
    const float* W_h   = (const float*)d_in[4];
    const float* b_h   = (const float*)d_in[5];
    const float* W_out = (const float*)d_in[6];
    const float* b_out = (const float*)d_in[7];
    float* out = (float*)d_out;

    int N = in_sizes[0] / 4;
    int E = in_sizes[1] / 2;
    const int* src = ei;
    const int* dst = ei + E;

    char* ws = (char*)d_ws;
    bf16* gA        = (bf16*)ws;   ws += (size_t)N * 64 * 2;
    bf16* gB        = (bf16*)ws;   ws += (size_t)N * 64 * 2;
    int*  bucket    = (int*)ws;    ws += (size_t)E * 4;
    int*  row_start = (int*)ws;    ws += (size_t)(N + 1) * 4;
    int*  cursor    = (int*)ws;    ws += (size_t)N * 4;
    int*  cnt       = (int*)ws;    ws += (size_t)N * 4;
    float* dinv     = (float*)ws;  ws += (size_t)N * 4;
    float* zg       = (float*)ws;  ws += (size_t)N * 4;
    int*  bsum      = (int*)ws;    // 257 ints

    int gN  = (N + TPB - 1) / TPB;       // scan chunk count (<=256 for N<=65536)
    int gE  = (E + TPB - 1) / TPB;
    int gNF = (N * 64 + TPB - 1) / TPB;
    int gN4 = (N + 3) / 4;               // 4 nodes/block (1 wave per node)

    // ---- CSR build + norms ----
    k_zero_cnt<<<gN, TPB, 0, stream>>>(cnt, N);
    k_hist<<<gE, TPB, 0, stream>>>(dst, cnt, E, N);
    k_blocksum<<<gN, TPB, 0, stream>>>(cnt, bsum, N);
    k_scan_bsum<<<1, TPB, 0, stream>>>(bsum, gN);
    k_scan_final<<<gN, TPB, 0, stream>>>(cnt, bsum, row_start, cursor, dinv, N);
    k_scatter<<<gE, TPB, 0, stream>>>(src, dst, cursor, bucket, E, N);

    // ---- layers (all feature buffers premultiplied by dinv) ----
    k_mm_in<<<gNF, TPB, 0, stream>>>(x, W_in, dinv, gA, N);
    k_gconv<<<gN4, TPB, 0, stream>>>(gA, dinv, row_start, bucket, b_in, W_h, gB, N, E);
    k_gconv<<<gN4, TPB, 0, stream>>>(gB, dinv, row_start, bucket, b_h, W_h + 4096, gA, N, E);
    k_gconv<<<gN4, TPB, 0, stream>>>(gA, dinv, row_start, bucket, b_h + 64, W_h + 8192, gB, N, E);
    k_gconv_z<<<gN4, TPB, 0, stream>>>(gB, dinv, row_start, bucket, b_h + 128, W_out, zg, N, E);
    k_out<<<gN4, TPB, 0, stream>>>(zg, dinv, row_start, bucket, b_out, out, N, E);
}